// Round 2
// baseline (1963.706 us; speedup 1.0000x reference)
//
#include <hip/hip_runtime.h>
#include <hip/hip_bf16.h>

#define N_NODES 50000
#define N_EDGES 800000
#define D 128
#define NH 8
#define DH 16
#define DFF 256
#define LN_EPS 1e-5f
#define TE 64
#define NB 8

// ---- monotonic float<->uint encoding for atomicMax on floats ----
__device__ __forceinline__ unsigned enc_f(float f) {
    unsigned u = __float_as_uint(f);
    return (u & 0x80000000u) ? ~u : (u | 0x80000000u);
}
__device__ __forceinline__ float dec_f(unsigned u) {
    return __uint_as_float((u & 0x80000000u) ? (u & 0x7fffffffu) : ~u);
}

__device__ __forceinline__ float wred(float v) {
#pragma unroll
    for (int o = 32; o; o >>= 1) v += __shfl_xor(v, o);
    return v;
}

// K1: q/k projections. 16 nodes per 128-thread block.
__global__ __launch_bounds__(128) void k_qkproj(
    const float* __restrict__ x, const float* __restrict__ Wk,
    const float* __restrict__ Wq, float* __restrict__ kout,
    float* __restrict__ qout) {
    __shared__ float xs[16][128];
    const int t = threadIdx.x;
    const int nb = blockIdx.x * 16;
#pragma unroll
    for (int r = 0; r < 16; ++r) xs[r][t] = x[(size_t)(nb + r) * D + t];
    __syncthreads();
    const float4* wk4 = (const float4*)(Wk + (size_t)t * D);
    const float4* wq4 = (const float4*)(Wq + (size_t)t * D);
    float ka[16] = {}, qa[16] = {};
#pragma unroll 4
    for (int i4 = 0; i4 < 32; ++i4) {
        float4 wk = wk4[i4], wq = wq4[i4];
#pragma unroll
        for (int r = 0; r < 16; ++r) {
            float4 xv = *(const float4*)&xs[r][i4 * 4];
            ka[r] += wk.x * xv.x + wk.y * xv.y + wk.z * xv.z + wk.w * xv.w;
            qa[r] += wq.x * xv.x + wq.y * xv.y + wq.z * xv.z + wq.w * xv.w;
        }
    }
#pragma unroll
    for (int r = 0; r < 16; ++r) {
        kout[(size_t)(nb + r) * D + t] = ka[r];
        qout[(size_t)(nb + r) * D + t] = qa[r];
    }
}

// K2: per-(edge,head) attention logit + segment max (encoded atomicMax).
__global__ __launch_bounds__(256) void k_logits(
    const float* __restrict__ kv, const float* __restrict__ qv,
    const float* __restrict__ basic, const float* __restrict__ Wdis,
    const int* __restrict__ src, const int* __restrict__ dst,
    float* __restrict__ logits, unsigned* __restrict__ menc) {
    int tid = blockIdx.x * 256 + threadIdx.x;
    int e = tid >> 3, h = tid & 7;
    int si = src[e], di = dst[e];
    const float4* kp = (const float4*)(kv + (size_t)si * D + h * DH);
    const float4* qp = (const float4*)(qv + (size_t)di * D + h * DH);
    float acc = 0.f;
#pragma unroll
    for (int i = 0; i < 4; ++i) {
        float4 a = kp[i], b = qp[i];
        acc += a.x * b.x + a.y * b.y + a.z * b.z + a.w * b.w;
    }
    float lg = acc * 0.25f + basic[e] * Wdis[h];
    logits[tid] = lg;
    atomicMax(&menc[(size_t)di * NH + h], enc_f(lg));
}

// K3: p = exp(logit - m[dst]); accumulate s. Overwrites logits with p.
__global__ __launch_bounds__(256) void k_exp(
    const int* __restrict__ dst, const unsigned* __restrict__ menc,
    float* __restrict__ logits, float* __restrict__ ssum) {
    int tid = blockIdx.x * 256 + threadIdx.x;
    int e = tid >> 3, h = tid & 7;
    int di = dst[e];
    float m = dec_f(menc[(size_t)di * NH + h]);
    float p = expf(logits[tid] - m);
    logits[tid] = p;
    atomicAdd(&ssum[(size_t)di * NH + h], p);
}

// K4: fused v = bond @ Wv.T (tile 64 edges x 128 cols, K chunked by 64)
//     epilogue: scale by a = p/s[dst] and atomicAdd into ft[dst].
__global__ __launch_bounds__(256) void k_scatter(
    const float* __restrict__ bond, const float* __restrict__ Wv,
    const float* __restrict__ pbuf, const float* __restrict__ ssum,
    const int* __restrict__ dst, float* __restrict__ ft) {
    __shared__ float As[64][68];   // [k][edge], padded, 16B-aligned rows
    __shared__ float Bs[64][132];  // [k][col],  padded, 16B-aligned rows
    const int t = threadIdx.x;
    const int e0 = blockIdx.x * TE;
    const int eg = t >> 5, cg = t & 31;
    float4 acc4[8];
#pragma unroll
    for (int j = 0; j < 8; ++j) acc4[j] = make_float4(0.f, 0.f, 0.f, 0.f);

    for (int kc = 0; kc < 128; kc += 64) {
        __syncthreads();
        for (int idx = t; idx < 128 * 64; idx += 256) {
            int r = idx >> 6, kk = idx & 63;
            Bs[kk][r] = Wv[(size_t)r * D + kc + kk];
        }
        for (int idx = t; idx < TE * 64; idx += 256) {
            int el = idx >> 6, kk = idx & 63;
            As[kk][el] = bond[(size_t)(e0 + el) * D + kc + kk];
        }
        __syncthreads();
#pragma unroll 4
        for (int kk = 0; kk < 64; ++kk) {
            float4 bv = *(const float4*)&Bs[kk][cg * 4];
            float4 a0 = *(const float4*)&As[kk][eg * 8];
            float4 a1 = *(const float4*)&As[kk][eg * 8 + 4];
            float ae[8] = {a0.x, a0.y, a0.z, a0.w, a1.x, a1.y, a1.z, a1.w};
#pragma unroll
            for (int j = 0; j < 8; ++j) {
                acc4[j].x += ae[j] * bv.x;
                acc4[j].y += ae[j] * bv.y;
                acc4[j].z += ae[j] * bv.z;
                acc4[j].w += ae[j] * bv.w;
            }
        }
    }
    const int h = cg >> 2, c0 = cg * 4;
#pragma unroll
    for (int j = 0; j < 8; ++j) {
        int e = e0 + eg * 8 + j;
        int di = dst[e];
        float a = pbuf[(size_t)e * NH + h] / ssum[(size_t)di * NH + h];
        float* fp = ft + (size_t)di * D + c0;
        atomicAdd(fp + 0, acc4[j].x * a);
        atomicAdd(fp + 1, acc4[j].y * a);
        atomicAdd(fp + 2, acc4[j].z * a);
        atomicAdd(fp + 3, acc4[j].w * a);
    }
}

// K5: per-node beta gate -> LN1 -> FFN -> residual -> LN2 -> f32 out.
// 8 nodes per 256-thread block; halves (128 thr) own alternating nodes.
__global__ __launch_bounds__(256) void k_node(
    const float* __restrict__ ft, const float* __restrict__ x,
    const float* __restrict__ Wb, const float* __restrict__ W1,
    const float* __restrict__ W2, const float* __restrict__ g_ln,
    const float* __restrict__ b_ln, float* __restrict__ out) {
    __shared__ float hln[NB][128];
    __shared__ float hs[NB][128];
    __shared__ float hid[NB][256];
    __shared__ float red[4];
    const int t = threadIdx.x;
    const int g = t >> 7;   // half id
    const int tt = t & 127;
    const int w = t >> 6;   // wave id
    const int nb = blockIdx.x * NB;

    auto hred = [&](float v) -> float {
        float r = wred(v);
        if ((t & 63) == 0) red[w] = r;
        __syncthreads();
        float s = red[g * 2] + red[g * 2 + 1];
        __syncthreads();
        return s;
    };

    // Phase A: beta gating + LN1
    for (int np = 0; np < NB / 2; ++np) {
        int n = np * 2 + g;
        float fv = ft[(size_t)(nb + n) * D + tt];
        float xv = x[(size_t)(nb + n) * D + tt];
        float bsum = hred(fv * Wb[tt] + xv * Wb[128 + tt] + (fv - xv) * Wb[256 + tt]);
        float beta = 1.f / (1.f + expf(-bsum));
        float he = beta * xv + (1.f - beta) * fv;
        hs[n][tt] = he;
        float mu = hred(he) * (1.f / 128.f);
        float d = he - mu;
        float var = hred(d * d) * (1.f / 128.f);
        hln[n][tt] = d * rsqrtf(var + LN_EPS) * g_ln[tt] + b_ln[tt];
    }
    __syncthreads();
    // Phase B: hidden = relu(hln @ W1.T); thread t owns hidden col t.
    {
        const float4* w1p = (const float4*)(W1 + (size_t)t * D);
        float acc[NB] = {};
        for (int i4 = 0; i4 < 32; ++i4) {
            float4 wv = w1p[i4];
#pragma unroll
            for (int n = 0; n < NB; ++n) {
                float4 hv = *(const float4*)&hln[n][i4 * 4];
                acc[n] += wv.x * hv.x + wv.y * hv.y + wv.z * hv.z + wv.w * hv.w;
            }
        }
#pragma unroll
        for (int n = 0; n < NB; ++n) hid[n][t] = fmaxf(acc[n], 0.f);
    }
    __syncthreads();
    // Phase C: y = hid @ W2.T + residual; half g owns nodes g*4..g*4+3.
    {
        const float4* w2p = (const float4*)(W2 + (size_t)tt * DFF);
        float acc[NB / 2] = {};
        for (int u4 = 0; u4 < 64; ++u4) {
            float4 wv = w2p[u4];
#pragma unroll
            for (int m = 0; m < NB / 2; ++m) {
                int n = g * (NB / 2) + m;
                float4 hv = *(const float4*)&hid[n][u4 * 4];
                acc[m] += wv.x * hv.x + wv.y * hv.y + wv.z * hv.z + wv.w * hv.w;
            }
        }
        __syncthreads();
#pragma unroll
        for (int m = 0; m < NB / 2; ++m) {
            int n = g * (NB / 2) + m;
            hln[n][tt] = acc[m] + hs[n][tt];  // reuse hln as y
        }
    }
    __syncthreads();
    // Phase D: final non-affine LN + f32 store
    for (int np = 0; np < NB / 2; ++np) {
        int n = np * 2 + g;
        float y = hln[n][tt];
        float mu = hred(y) * (1.f / 128.f);
        float d = y - mu;
        float var = hred(d * d) * (1.f / 128.f);
        out[(size_t)(nb + n) * D + tt] = d * rsqrtf(var + LN_EPS);
    }
}

extern "C" void kernel_launch(void* const* d_in, const int* in_sizes, int n_in,
                              void* d_out, int out_size, void* d_ws, size_t ws_size,
                              hipStream_t stream) {
    const float* bond = (const float*)d_in[0];
    const float* x    = (const float*)d_in[1];
    const float* basic= (const float*)d_in[2];
    const float* Wk   = (const float*)d_in[3];
    const float* Wq   = (const float*)d_in[4];
    const float* Wv   = (const float*)d_in[5];
    const float* Wdis = (const float*)d_in[6];
    const float* Wb   = (const float*)d_in[7];
    const float* W1   = (const float*)d_in[8];
    const float* W2   = (const float*)d_in[9];
    const float* g_ln = (const float*)d_in[10];
    const float* b_ln = (const float*)d_in[11];
    const int* src    = (const int*)d_in[12];
    const int* dst    = (const int*)d_in[13];
    float* out = (float*)d_out;

    float* ws = (float*)d_ws;
    float* kbuf = ws;                                    // N*128
    float* qbuf = kbuf + (size_t)N_NODES * D;            // N*128
    float* logits = qbuf + (size_t)N_NODES * D;          // E*8 (becomes p)
    unsigned* menc = (unsigned*)(logits + (size_t)N_EDGES * NH);  // N*8
    float* ssum = (float*)(menc + (size_t)N_NODES * NH); // N*8
    float* ftb = ssum + (size_t)N_NODES * NH;            // N*128

    // zero m_enc (0 encodes below any finite logit), s, ft — contiguous
    size_t zbytes = ((size_t)N_NODES * NH * 2 + (size_t)N_NODES * D) * sizeof(float);
    hipMemsetAsync(menc, 0, zbytes, stream);

    k_qkproj<<<N_NODES / 16, 128, 0, stream>>>(x, Wk, Wq, kbuf, qbuf);
    k_logits<<<(N_EDGES * NH) / 256, 256, 0, stream>>>(kbuf, qbuf, basic, Wdis,
                                                       src, dst, logits, menc);
    k_exp<<<(N_EDGES * NH) / 256, 256, 0, stream>>>(dst, menc, logits, ssum);
    k_scatter<<<N_EDGES / TE, 256, 0, stream>>>(bond, Wv, logits, ssum, dst, ftb);
    k_node<<<N_NODES / NB, 256, 0, stream>>>(ftb, x, Wb, W1, W2, g_ln, b_ln, out);
}

// Round 3
// 1345.075 us; speedup vs baseline: 1.4599x; 1.4599x over previous
//
#include <hip/hip_runtime.h>
#include <hip/hip_bf16.h>

#define N_NODES 50000
#define N_EDGES 800000
#define D 128
#define NH 8
#define DH 16
#define DFF 256
#define LN_EPS 1e-5f
#define NB 8
#define GN 8
#define KC 32
#define SCAN_BS 512
#define NSCAN ((N_NODES + SCAN_BS - 1) / SCAN_BS)  // 98

// ---- monotonic float<->uint encoding for atomicMax on floats ----
__device__ __forceinline__ unsigned enc_f(float f) {
    unsigned u = __float_as_uint(f);
    return (u & 0x80000000u) ? ~u : (u | 0x80000000u);
}
__device__ __forceinline__ float dec_f(unsigned u) {
    return __uint_as_float((u & 0x80000000u) ? (u & 0x7fffffffu) : ~u);
}

__device__ __forceinline__ float wred(float v) {
#pragma unroll
    for (int o = 32; o; o >>= 1) v += __shfl_xor(v, o);
    return v;
}

// K1: q/k projections. 16 nodes per 128-thread block.
__global__ __launch_bounds__(128) void k_qkproj(
    const float* __restrict__ x, const float* __restrict__ Wk,
    const float* __restrict__ Wq, float* __restrict__ kout,
    float* __restrict__ qout) {
    __shared__ float xs[16][128];
    const int t = threadIdx.x;
    const int nb = blockIdx.x * 16;
#pragma unroll
    for (int r = 0; r < 16; ++r) xs[r][t] = x[(size_t)(nb + r) * D + t];
    __syncthreads();
    const float4* wk4 = (const float4*)(Wk + (size_t)t * D);
    const float4* wq4 = (const float4*)(Wq + (size_t)t * D);
    float ka[16] = {}, qa[16] = {};
#pragma unroll 4
    for (int i4 = 0; i4 < 32; ++i4) {
        float4 wk = wk4[i4], wq = wq4[i4];
#pragma unroll
        for (int r = 0; r < 16; ++r) {
            float4 xv = *(const float4*)&xs[r][i4 * 4];
            ka[r] += wk.x * xv.x + wk.y * xv.y + wk.z * xv.z + wk.w * xv.w;
            qa[r] += wq.x * xv.x + wq.y * xv.y + wq.z * xv.z + wq.w * xv.w;
        }
    }
#pragma unroll
    for (int r = 0; r < 16; ++r) {
        kout[(size_t)(nb + r) * D + t] = ka[r];
        qout[(size_t)(nb + r) * D + t] = qa[r];
    }
}

// K2: per-(edge,head) attention logit + segment max (encoded atomicMax).
__global__ __launch_bounds__(256) void k_logits(
    const float* __restrict__ kv, const float* __restrict__ qv,
    const float* __restrict__ basic, const float* __restrict__ Wdis,
    const int* __restrict__ src, const int* __restrict__ dst,
    float* __restrict__ logits, unsigned* __restrict__ menc) {
    int tid = blockIdx.x * 256 + threadIdx.x;
    int e = tid >> 3, h = tid & 7;
    int si = src[e], di = dst[e];
    const float4* kp = (const float4*)(kv + (size_t)si * D + h * DH);
    const float4* qp = (const float4*)(qv + (size_t)di * D + h * DH);
    float acc = 0.f;
#pragma unroll
    for (int i = 0; i < 4; ++i) {
        float4 a = kp[i], b = qp[i];
        acc += a.x * b.x + a.y * b.y + a.z * b.z + a.w * b.w;
    }
    float lg = acc * 0.25f + basic[e] * Wdis[h];
    logits[tid] = lg;
    atomicMax(&menc[(size_t)di * NH + h], enc_f(lg));
}

// K3: p = exp(logit - m[dst]); accumulate s. Overwrites logits with p.
__global__ __launch_bounds__(256) void k_exp(
    const int* __restrict__ dst, const unsigned* __restrict__ menc,
    float* __restrict__ logits, float* __restrict__ ssum) {
    int tid = blockIdx.x * 256 + threadIdx.x;
    int e = tid >> 3, h = tid & 7;
    int di = dst[e];
    float m = dec_f(menc[(size_t)di * NH + h]);
    float p = expf(logits[tid] - m);
    logits[tid] = p;
    atomicAdd(&ssum[(size_t)di * NH + h], p);
}

// CSR build ---------------------------------------------------------------
__global__ __launch_bounds__(256) void k_hist(const int* __restrict__ dst,
                                              int* __restrict__ deg) {
    int e = blockIdx.x * 256 + threadIdx.x;
    atomicAdd(&deg[dst[e]], 1);
}

__global__ __launch_bounds__(SCAN_BS) void k_scan1(
    const int* __restrict__ deg, int* __restrict__ scanout,
    int* __restrict__ bsum) {
    __shared__ int ss[SCAN_BS];
    const int t = threadIdx.x;
    const int i = blockIdx.x * SCAN_BS + t;
    int v = (i < N_NODES) ? deg[i] : 0;
    ss[t] = v;
    __syncthreads();
    for (int off = 1; off < SCAN_BS; off <<= 1) {
        int a = (t >= off) ? ss[t - off] : 0;
        __syncthreads();
        ss[t] += a;
        __syncthreads();
    }
    if (i < N_NODES) scanout[i] = ss[t] - v;  // exclusive within block
    if (t == SCAN_BS - 1) bsum[blockIdx.x] = ss[t];
}

__global__ __launch_bounds__(128) void k_scan2(int* __restrict__ bsum) {
    __shared__ int ss[128];
    const int t = threadIdx.x;
    int v = (t < NSCAN) ? bsum[t] : 0;
    ss[t] = v;
    __syncthreads();
    for (int off = 1; off < 128; off <<= 1) {
        int a = (t >= off) ? ss[t - off] : 0;
        __syncthreads();
        ss[t] += a;
        __syncthreads();
    }
    if (t < NSCAN) bsum[t] = ss[t] - v;  // exclusive across blocks
}

__global__ __launch_bounds__(256) void k_scan3(
    const int* __restrict__ scanout, const int* __restrict__ bsum,
    int* __restrict__ rowstart, int* __restrict__ cursor) {
    int i = blockIdx.x * 256 + threadIdx.x;
    if (i < N_NODES) {
        int rs = scanout[i] + bsum[i / SCAN_BS];
        rowstart[i] = rs;
        cursor[i] = rs;
    }
    if (i == 0) rowstart[N_NODES] = N_EDGES;
}

__global__ __launch_bounds__(256) void k_fill(const int* __restrict__ dst,
                                              int* __restrict__ cursor,
                                              int* __restrict__ eidx) {
    int e = blockIdx.x * 256 + threadIdx.x;
    int pos = atomicAdd(&cursor[dst[e]], 1);
    eidx[pos] = e;
}

// a = p / s[dst]
__global__ __launch_bounds__(256) void k_norm(
    const int* __restrict__ dst, const float* __restrict__ ssum,
    const float* __restrict__ pbuf, float* __restrict__ abuf) {
    int i = blockIdx.x * 256 + threadIdx.x;
    int e = i >> 3, h = i & 7;
    abuf[i] = pbuf[i] / ssum[(size_t)dst[e] * NH + h];
}

// K4': per-block 8 dst nodes; tile GEMM over their (sorted) edges;
// per-thread run-length merge -> LDS accumulate -> direct coalesced store.
__global__ __launch_bounds__(256) void k_gather(
    const float* __restrict__ bond, const float* __restrict__ Wv,
    const float* __restrict__ abuf, const int* __restrict__ rowstart,
    const int* __restrict__ eidx, float* __restrict__ ft) {
    __shared__ float As[KC][68];    // [k][edge]
    __shared__ float Bs[KC][132];   // [k][col]
    __shared__ float facc[GN][128];
    __shared__ int se[64];
    __shared__ int srs[GN + 1];
    const int t = threadIdx.x;
    const int n0 = blockIdx.x * GN;
    if (t < GN + 1) srs[t] = rowstart[n0 + t];
    for (int i = t; i < GN * 128; i += 256) ((float*)facc)[i] = 0.f;
    __syncthreads();
    const int rs0 = srs[0];
    const int total = srs[GN] - rs0;
    const int eg = t >> 5, cg = t & 31, h = cg >> 2, c0 = cg * 4;

    for (int base = 0; base < total; base += 64) {
        __syncthreads();  // protect se rewrite vs previous iteration
        if (t < 64) se[t] = (base + t < total) ? eidx[rs0 + base + t] : -1;
        float4 acc[8];
#pragma unroll
        for (int j = 0; j < 8; ++j) acc[j] = make_float4(0.f, 0.f, 0.f, 0.f);
        for (int kc = 0; kc < 128; kc += KC) {
            __syncthreads();
            for (int idx = t; idx < 128 * KC; idx += 256) {
                int r = idx >> 5, kk = idx & 31;
                Bs[kk][r] = Wv[(size_t)r * D + kc + kk];
            }
            for (int idx = t; idx < 64 * KC; idx += 256) {
                int el = idx >> 5, kk = idx & 31;
                int e = se[el];
                As[kk][el] = (e >= 0) ? bond[(size_t)e * D + kc + kk] : 0.f;
            }
            __syncthreads();
#pragma unroll 4
            for (int kk = 0; kk < KC; ++kk) {
                float4 bv = *(const float4*)&Bs[kk][c0];
                float4 a0 = *(const float4*)&As[kk][eg * 8];
                float4 a1 = *(const float4*)&As[kk][eg * 8 + 4];
                float ae[8] = {a0.x, a0.y, a0.z, a0.w, a1.x, a1.y, a1.z, a1.w};
#pragma unroll
                for (int j = 0; j < 8; ++j) {
                    acc[j].x += ae[j] * bv.x;
                    acc[j].y += ae[j] * bv.y;
                    acc[j].z += ae[j] * bv.z;
                    acc[j].w += ae[j] * bv.w;
                }
            }
        }
        // epilogue: scale by a, run-length merge by local node, LDS atomics
        int relb = base + eg * 8;
        float4 m = make_float4(0.f, 0.f, 0.f, 0.f);
        int curln = -1;
#pragma unroll
        for (int j = 0; j < 8; ++j) {
            int rel = relb + j;
            if (rel < total) {
                int gpos = rs0 + rel;
                int ln = 0;
#pragma unroll
                for (int q = 1; q < GN; ++q) ln += (gpos >= srs[q]);
                float a = abuf[(size_t)se[eg * 8 + j] * NH + h];
                if (ln != curln) {
                    if (curln >= 0) {
                        atomicAdd(&facc[curln][c0 + 0], m.x);
                        atomicAdd(&facc[curln][c0 + 1], m.y);
                        atomicAdd(&facc[curln][c0 + 2], m.z);
                        atomicAdd(&facc[curln][c0 + 3], m.w);
                    }
                    m = make_float4(0.f, 0.f, 0.f, 0.f);
                    curln = ln;
                }
                m.x += a * acc[j].x;
                m.y += a * acc[j].y;
                m.z += a * acc[j].z;
                m.w += a * acc[j].w;
            }
        }
        if (curln >= 0) {
            atomicAdd(&facc[curln][c0 + 0], m.x);
            atomicAdd(&facc[curln][c0 + 1], m.y);
            atomicAdd(&facc[curln][c0 + 2], m.z);
            atomicAdd(&facc[curln][c0 + 3], m.w);
        }
    }
    __syncthreads();
    for (int i = t; i < GN * 128; i += 256)
        ft[(size_t)n0 * D + i] = ((float*)facc)[i];
}

// K5: per-node beta gate -> LN1 -> FFN -> residual -> LN2 -> f32 out.
__global__ __launch_bounds__(256) void k_node(
    const float* __restrict__ ft, const float* __restrict__ x,
    const float* __restrict__ Wb, const float* __restrict__ W1,
    const float* __restrict__ W2, const float* __restrict__ g_ln,
    const float* __restrict__ b_ln, float* __restrict__ out) {
    __shared__ float hln[NB][128];
    __shared__ float hs[NB][128];
    __shared__ float hid[NB][256];
    __shared__ float red[4];
    const int t = threadIdx.x;
    const int g = t >> 7;
    const int tt = t & 127;
    const int w = t >> 6;
    const int nb = blockIdx.x * NB;

    auto hred = [&](float v) -> float {
        float r = wred(v);
        if ((t & 63) == 0) red[w] = r;
        __syncthreads();
        float s = red[g * 2] + red[g * 2 + 1];
        __syncthreads();
        return s;
    };

    for (int np = 0; np < NB / 2; ++np) {
        int n = np * 2 + g;
        float fv = ft[(size_t)(nb + n) * D + tt];
        float xv = x[(size_t)(nb + n) * D + tt];
        float bsum = hred(fv * Wb[tt] + xv * Wb[128 + tt] + (fv - xv) * Wb[256 + tt]);
        float beta = 1.f / (1.f + expf(-bsum));
        float he = beta * xv + (1.f - beta) * fv;
        hs[n][tt] = he;
        float mu = hred(he) * (1.f / 128.f);
        float d = he - mu;
        float var = hred(d * d) * (1.f / 128.f);
        hln[n][tt] = d * rsqrtf(var + LN_EPS) * g_ln[tt] + b_ln[tt];
    }
    __syncthreads();
    {
        const float4* w1p = (const float4*)(W1 + (size_t)t * D);
        float acc[NB] = {};
        for (int i4 = 0; i4 < 32; ++i4) {
            float4 wv = w1p[i4];
#pragma unroll
            for (int n = 0; n < NB; ++n) {
                float4 hv = *(const float4*)&hln[n][i4 * 4];
                acc[n] += wv.x * hv.x + wv.y * hv.y + wv.z * hv.z + wv.w * hv.w;
            }
        }
#pragma unroll
        for (int n = 0; n < NB; ++n) hid[n][t] = fmaxf(acc[n], 0.f);
    }
    __syncthreads();
    {
        const float4* w2p = (const float4*)(W2 + (size_t)tt * DFF);
        float acc[NB / 2] = {};
        for (int u4 = 0; u4 < 64; ++u4) {
            float4 wv = w2p[u4];
#pragma unroll
            for (int m = 0; m < NB / 2; ++m) {
                int n = g * (NB / 2) + m;
                float4 hv = *(const float4*)&hid[n][u4 * 4];
                acc[m] += wv.x * hv.x + wv.y * hv.y + wv.z * hv.z + wv.w * hv.w;
            }
        }
        __syncthreads();
#pragma unroll
        for (int m = 0; m < NB / 2; ++m) {
            int n = g * (NB / 2) + m;
            hln[n][tt] = acc[m] + hs[n][tt];
        }
    }
    __syncthreads();
    for (int np = 0; np < NB / 2; ++np) {
        int n = np * 2 + g;
        float y = hln[n][tt];
        float mu = hred(y) * (1.f / 128.f);
        float d = y - mu;
        float var = hred(d * d) * (1.f / 128.f);
        out[(size_t)(nb + n) * D + tt] = d * rsqrtf(var + LN_EPS);
    }
}

extern "C" void kernel_launch(void* const* d_in, const int* in_sizes, int n_in,
                              void* d_out, int out_size, void* d_ws, size_t ws_size,
                              hipStream_t stream) {
    const float* bond = (const float*)d_in[0];
    const float* x    = (const float*)d_in[1];
    const float* basic= (const float*)d_in[2];
    const float* Wk   = (const float*)d_in[3];
    const float* Wq   = (const float*)d_in[4];
    const float* Wv   = (const float*)d_in[5];
    const float* Wdis = (const float*)d_in[6];
    const float* Wb   = (const float*)d_in[7];
    const float* W1   = (const float*)d_in[8];
    const float* W2   = (const float*)d_in[9];
    const float* g_ln = (const float*)d_in[10];
    const float* b_ln = (const float*)d_in[11];
    const int* src    = (const int*)d_in[12];
    const int* dst    = (const int*)d_in[13];
    float* out = (float*)d_out;

    // ws layout (105.6 MB total, same footprint as round 2, via aliasing):
    float* ws = (float*)d_ws;
    float* kbuf = ws;                                  // N*128  [abuf aliases]
    float* qbuf = kbuf + (size_t)N_NODES * D;          // N*128  [CSR aliases]
    float* pbuf = qbuf + (size_t)N_NODES * D;          // E*8
    unsigned* menc = (unsigned*)(pbuf + (size_t)N_EDGES * NH);  // N*8 [zeroed]
    float* ssum = (float*)(menc + (size_t)N_NODES * NH);        // N*8 [zeroed]
    float* ftb = ssum + (size_t)N_NODES * NH;          // N*128

    float* abuf = kbuf;  // reuse: kbuf dead after k_logits
    int* csr = (int*)qbuf;  // reuse: qbuf dead after k_logits
    int* deg      = csr;                 // N        [zeroed after k_logits]
    int* scanout  = deg + N_NODES;       // N
    int* bsum     = scanout + N_NODES;   // 128
    int* rowstart = bsum + 128;          // N+1
    int* cursor   = rowstart + N_NODES + 1;  // N
    int* eidx     = cursor + N_NODES;    // E

    hipMemsetAsync(menc, 0, (size_t)N_NODES * NH * 2 * sizeof(float), stream);

    k_qkproj<<<N_NODES / 16, 128, 0, stream>>>(x, Wk, Wq, kbuf, qbuf);
    k_logits<<<(N_EDGES * NH) / 256, 256, 0, stream>>>(kbuf, qbuf, basic, Wdis,
                                                       src, dst, pbuf, menc);
    hipMemsetAsync(deg, 0, (size_t)N_NODES * sizeof(int), stream);  // qbuf now dead
    k_exp<<<(N_EDGES * NH) / 256, 256, 0, stream>>>(dst, menc, pbuf, ssum);
    k_hist<<<N_EDGES / 256, 256, 0, stream>>>(dst, deg);
    k_scan1<<<NSCAN, SCAN_BS, 0, stream>>>(deg, scanout, bsum);
    k_scan2<<<1, 128, 0, stream>>>(bsum);
    k_scan3<<<(N_NODES + 255) / 256, 256, 0, stream>>>(scanout, bsum, rowstart, cursor);
    k_fill<<<N_EDGES / 256, 256, 0, stream>>>(dst, cursor, eidx);
    k_norm<<<(N_EDGES * NH) / 256, 256, 0, stream>>>(dst, ssum, pbuf, abuf);
    k_gather<<<N_NODES / GN, 256, 0, stream>>>(bond, Wv, abuf, rowstart, eidx, ftb);
    k_node<<<N_NODES / NB, 256, 0, stream>>>(ftb, x, Wb, W1, W2, g_ln, b_ln, out);
}

// Round 4
// 976.882 us; speedup vs baseline: 2.0102x; 1.3769x over previous
//
#include <hip/hip_runtime.h>
#include <hip/hip_bf16.h>

#define N_NODES 50000
#define N_EDGES 800000
#define D 128
#define NH 8
#define DH 16
#define DFF 256
#define LN_EPS 1e-5f
#define NB 8
#define GN 8
#define SCAN_BS 512
#define NSCAN ((N_NODES + SCAN_BS - 1) / SCAN_BS)  // 98

typedef __attribute__((ext_vector_type(8))) short bf16x8;
typedef __attribute__((ext_vector_type(4))) float f32x4;

// ---- monotonic float<->uint encoding for atomicMax on floats ----
__device__ __forceinline__ unsigned enc_f(float f) {
    unsigned u = __float_as_uint(f);
    return (u & 0x80000000u) ? ~u : (u | 0x80000000u);
}
__device__ __forceinline__ float dec_f(unsigned u) {
    return __uint_as_float((u & 0x80000000u) ? (u & 0x7fffffffu) : ~u);
}

__device__ __forceinline__ float wred(float v) {
#pragma unroll
    for (int o = 32; o; o >>= 1) v += __shfl_xor(v, o);
    return v;
}

// fp32 -> bf16 (RNE) bit helper
__device__ __forceinline__ short f2b(float f) {
    unsigned u = __float_as_uint(f);
    unsigned r = u + 0x7fffu + ((u >> 16) & 1u);
    return (short)(r >> 16);
}

// K1: q/k projections. 16 nodes per 128-thread block.
__global__ __launch_bounds__(128) void k_qkproj(
    const float* __restrict__ x, const float* __restrict__ Wk,
    const float* __restrict__ Wq, float* __restrict__ kout,
    float* __restrict__ qout) {
    __shared__ float xs[16][128];
    const int t = threadIdx.x;
    const int nb = blockIdx.x * 16;
#pragma unroll
    for (int r = 0; r < 16; ++r) xs[r][t] = x[(size_t)(nb + r) * D + t];
    __syncthreads();
    const float4* wk4 = (const float4*)(Wk + (size_t)t * D);
    const float4* wq4 = (const float4*)(Wq + (size_t)t * D);
    float ka[16] = {}, qa[16] = {};
#pragma unroll 4
    for (int i4 = 0; i4 < 32; ++i4) {
        float4 wk = wk4[i4], wq = wq4[i4];
#pragma unroll
        for (int r = 0; r < 16; ++r) {
            float4 xv = *(const float4*)&xs[r][i4 * 4];
            ka[r] += wk.x * xv.x + wk.y * xv.y + wk.z * xv.z + wk.w * xv.w;
            qa[r] += wq.x * xv.x + wq.y * xv.y + wq.z * xv.z + wq.w * xv.w;
        }
    }
#pragma unroll
    for (int r = 0; r < 16; ++r) {
        kout[(size_t)(nb + r) * D + t] = ka[r];
        qout[(size_t)(nb + r) * D + t] = qa[r];
    }
}

// K2: per-(edge,head) attention logit + segment max (encoded atomicMax).
__global__ __launch_bounds__(256) void k_logits(
    const float* __restrict__ kv, const float* __restrict__ qv,
    const float* __restrict__ basic, const float* __restrict__ Wdis,
    const int* __restrict__ src, const int* __restrict__ dst,
    float* __restrict__ logits, unsigned* __restrict__ menc) {
    int tid = blockIdx.x * 256 + threadIdx.x;
    int e = tid >> 3, h = tid & 7;
    int si = src[e], di = dst[e];
    const float4* kp = (const float4*)(kv + (size_t)si * D + h * DH);
    const float4* qp = (const float4*)(qv + (size_t)di * D + h * DH);
    float acc = 0.f;
#pragma unroll
    for (int i = 0; i < 4; ++i) {
        float4 a = kp[i], b = qp[i];
        acc += a.x * b.x + a.y * b.y + a.z * b.z + a.w * b.w;
    }
    float lg = acc * 0.25f + basic[e] * Wdis[h];
    logits[tid] = lg;
    atomicMax(&menc[(size_t)di * NH + h], enc_f(lg));
}

// K3: p = exp(logit - m[dst]); accumulate s. Overwrites logits with p.
__global__ __launch_bounds__(256) void k_exp(
    const int* __restrict__ dst, const unsigned* __restrict__ menc,
    float* __restrict__ logits, float* __restrict__ ssum) {
    int tid = blockIdx.x * 256 + threadIdx.x;
    int e = tid >> 3, h = tid & 7;
    int di = dst[e];
    float m = dec_f(menc[(size_t)di * NH + h]);
    float p = expf(logits[tid] - m);
    logits[tid] = p;
    atomicAdd(&ssum[(size_t)di * NH + h], p);
}

// CSR build ---------------------------------------------------------------
__global__ __launch_bounds__(256) void k_hist(const int* __restrict__ dst,
                                              int* __restrict__ deg) {
    int e = blockIdx.x * 256 + threadIdx.x;
    atomicAdd(&deg[dst[e]], 1);
}

__global__ __launch_bounds__(SCAN_BS) void k_scan1(
    const int* __restrict__ deg, int* __restrict__ scanout,
    int* __restrict__ bsum) {
    __shared__ int ss[SCAN_BS];
    const int t = threadIdx.x;
    const int i = blockIdx.x * SCAN_BS + t;
    int v = (i < N_NODES) ? deg[i] : 0;
    ss[t] = v;
    __syncthreads();
    for (int off = 1; off < SCAN_BS; off <<= 1) {
        int a = (t >= off) ? ss[t - off] : 0;
        __syncthreads();
        ss[t] += a;
        __syncthreads();
    }
    if (i < N_NODES) scanout[i] = ss[t] - v;  // exclusive within block
    if (t == SCAN_BS - 1) bsum[blockIdx.x] = ss[t];
}

__global__ __launch_bounds__(128) void k_scan2(int* __restrict__ bsum) {
    __shared__ int ss[128];
    const int t = threadIdx.x;
    int v = (t < NSCAN) ? bsum[t] : 0;
    ss[t] = v;
    __syncthreads();
    for (int off = 1; off < 128; off <<= 1) {
        int a = (t >= off) ? ss[t - off] : 0;
        __syncthreads();
        ss[t] += a;
        __syncthreads();
    }
    if (t < NSCAN) bsum[t] = ss[t] - v;  // exclusive across blocks
}

__global__ __launch_bounds__(256) void k_scan3(
    const int* __restrict__ scanout, const int* __restrict__ bsum,
    int* __restrict__ rowstart, int* __restrict__ cursor) {
    int i = blockIdx.x * 256 + threadIdx.x;
    if (i < N_NODES) {
        int rs = scanout[i] + bsum[i / SCAN_BS];
        rowstart[i] = rs;
        cursor[i] = rs;
    }
    if (i == 0) rowstart[N_NODES] = N_EDGES;
}

__global__ __launch_bounds__(256) void k_fill(const int* __restrict__ dst,
                                              int* __restrict__ cursor,
                                              int* __restrict__ eidx) {
    int e = blockIdx.x * 256 + threadIdx.x;
    int pos = atomicAdd(&cursor[dst[e]], 1);
    eidx[pos] = e;
}

// a = p / s[dst]
__global__ __launch_bounds__(256) void k_norm(
    const int* __restrict__ dst, const float* __restrict__ ssum,
    const float* __restrict__ pbuf, float* __restrict__ abuf) {
    int i = blockIdx.x * 256 + threadIdx.x;
    int e = i >> 3, h = i & 7;
    abuf[i] = pbuf[i] / ssum[(size_t)dst[e] * NH + h];
}

// K4: MFMA gather-GEMM. Per block: 8 dst nodes, bf16 v = bond @ Wv.T on
// matrix cores, run-length-merged LDS accumulate, coalesced ft store.
__global__ __launch_bounds__(256) void k_gather(
    const float* __restrict__ bond, const float* __restrict__ Wv,
    const float* __restrict__ abuf, const int* __restrict__ rowstart,
    const int* __restrict__ eidx, float* __restrict__ ft) {
    __shared__ short Blds[128 * 128];  // Wv bf16, [col][k], XOR-swizzled
    __shared__ short Alds[64 * 128];   // bond tile bf16, [edge][k], swizzled
    __shared__ float facc[GN * 128];
    __shared__ float salds[64 * 8];    // attn weights [edge][head]
    __shared__ int se[64];
    __shared__ int srs[GN + 1];
    const int t = threadIdx.x;
    const int n0 = blockIdx.x * GN;
    const int lane = t & 63, w = t >> 6;
    const int lr = lane & 15, lg = lane >> 4;

    if (t < GN + 1) srs[t] = rowstart[n0 + t];
    for (int i = t; i < GN * 128; i += 256) facc[i] = 0.f;
    // stage Wv as bf16 (once): row=out col c, 16 chunks of 8 bf16, swizzled
#pragma unroll
    for (int i = 0; i < 8; ++i) {
        int cid = i * 256 + t;
        int row = cid >> 4, cx = cid & 15;
        const float4* gp = (const float4*)(Wv + (size_t)row * D + cx * 8);
        float4 f0 = gp[0], f1 = gp[1];
        bf16x8 v;
        v[0] = f2b(f0.x); v[1] = f2b(f0.y); v[2] = f2b(f0.z); v[3] = f2b(f0.w);
        v[4] = f2b(f1.x); v[5] = f2b(f1.y); v[6] = f2b(f1.z); v[7] = f2b(f1.w);
        *(bf16x8*)&Blds[row * 128 + ((cx ^ (row & 7)) << 3)] = v;
    }
    __syncthreads();
    const int rs0 = srs[0];
    const int total = srs[GN] - rs0;

    for (int base = 0; base < total; base += 64) {
        __syncthreads();  // prev tile fully consumed
        if (t < 64) se[t] = (base + t < total) ? eidx[rs0 + base + t] : -1;
        __syncthreads();
        // stage bond tile (bf16, swizzled) + attn weights
#pragma unroll
        for (int i = 0; i < 4; ++i) {
            int cid = i * 256 + t;
            int row = cid >> 4, cx = cid & 15;
            int e = se[row];
            bf16x8 v = {0, 0, 0, 0, 0, 0, 0, 0};
            if (e >= 0) {
                const float4* gp = (const float4*)(bond + (size_t)e * D + cx * 8);
                float4 f0 = gp[0], f1 = gp[1];
                v[0] = f2b(f0.x); v[1] = f2b(f0.y); v[2] = f2b(f0.z); v[3] = f2b(f0.w);
                v[4] = f2b(f1.x); v[5] = f2b(f1.y); v[6] = f2b(f1.z); v[7] = f2b(f1.w);
            }
            *(bf16x8*)&Alds[row * 128 + ((cx ^ (row & 7)) << 3)] = v;
        }
#pragma unroll
        for (int i = 0; i < 2; ++i) {
            int idx = i * 256 + t;
            int e = se[idx >> 3];
            salds[idx] = (e >= 0) ? abuf[(size_t)e * NH + (idx & 7)] : 0.f;
        }
        __syncthreads();
        // MFMA: wave w owns edge rows w*16..+15, all 8 col tiles
        f32x4 acc[8];
#pragma unroll
        for (int n = 0; n < 8; ++n) acc[n] = (f32x4){0.f, 0.f, 0.f, 0.f};
#pragma unroll
        for (int ks = 0; ks < 4; ++ks) {
            int chunk = ks * 4 + lg;
            int am = w * 16 + lr;
            bf16x8 af = *(const bf16x8*)&Alds[am * 128 + ((chunk ^ (am & 7)) << 3)];
#pragma unroll
            for (int n = 0; n < 8; ++n) {
                int c = n * 16 + lr;
                bf16x8 bf = *(const bf16x8*)&Blds[c * 128 + ((chunk ^ (c & 7)) << 3)];
                acc[n] = __builtin_amdgcn_mfma_f32_16x16x32_bf16(af, bf, acc[n], 0, 0, 0);
            }
        }
        // epilogue: local-node ids for this lane's 4 edge rows
        int lnv[4], elv[4];
#pragma unroll
        for (int r = 0; r < 4; ++r) {
            int el = w * 16 + lg * 4 + r;
            elv[r] = el;
            int rel = base + el;
            int lnr = -1;
            if (rel < total) {
                int gpos = rs0 + rel;
                lnr = 0;
#pragma unroll
                for (int q = 1; q < GN; ++q) lnr += (gpos >= srs[q]);
            }
            lnv[r] = lnr;
        }
#pragma unroll
        for (int n = 0; n < 8; ++n) {
            int col = n * 16 + lr;
            float m = 0.f;
            int cur = -1;
#pragma unroll
            for (int r = 0; r < 4; ++r) {
                if (lnv[r] >= 0) {
                    float v = acc[n][r] * salds[elv[r] * 8 + n];
                    if (lnv[r] != cur) {
                        if (cur >= 0) atomicAdd(&facc[cur * 128 + col], m);
                        m = 0.f;
                        cur = lnv[r];
                    }
                    m += v;
                }
            }
            if (cur >= 0) atomicAdd(&facc[cur * 128 + col], m);
        }
    }
    __syncthreads();
    for (int i = t; i < GN * 128; i += 256)
        ft[(size_t)n0 * D + i] = facc[i];
}

// K5: per-node beta gate -> LN1 -> FFN -> residual -> LN2 -> f32 out.
__global__ __launch_bounds__(256) void k_node(
    const float* __restrict__ ft, const float* __restrict__ x,
    const float* __restrict__ Wb, const float* __restrict__ W1,
    const float* __restrict__ W2, const float* __restrict__ g_ln,
    const float* __restrict__ b_ln, float* __restrict__ out) {
    __shared__ float hln[NB][128];
    __shared__ float hs[NB][128];
    __shared__ float hid[NB][256];
    __shared__ float red[4];
    const int t = threadIdx.x;
    const int g = t >> 7;
    const int tt = t & 127;
    const int w = t >> 6;
    const int nb = blockIdx.x * NB;

    auto hred = [&](float v) -> float {
        float r = wred(v);
        if ((t & 63) == 0) red[w] = r;
        __syncthreads();
        float s = red[g * 2] + red[g * 2 + 1];
        __syncthreads();
        return s;
    };

    for (int np = 0; np < NB / 2; ++np) {
        int n = np * 2 + g;
        float fv = ft[(size_t)(nb + n) * D + tt];
        float xv = x[(size_t)(nb + n) * D + tt];
        float bsum = hred(fv * Wb[tt] + xv * Wb[128 + tt] + (fv - xv) * Wb[256 + tt]);
        float beta = 1.f / (1.f + expf(-bsum));
        float he = beta * xv + (1.f - beta) * fv;
        hs[n][tt] = he;
        float mu = hred(he) * (1.f / 128.f);
        float d = he - mu;
        float var = hred(d * d) * (1.f / 128.f);
        hln[n][tt] = d * rsqrtf(var + LN_EPS) * g_ln[tt] + b_ln[tt];
    }
    __syncthreads();
    {
        const float4* w1p = (const float4*)(W1 + (size_t)t * D);
        float acc[NB] = {};
        for (int i4 = 0; i4 < 32; ++i4) {
            float4 wv = w1p[i4];
#pragma unroll
            for (int n = 0; n < NB; ++n) {
                float4 hv = *(const float4*)&hln[n][i4 * 4];
                acc[n] += wv.x * hv.x + wv.y * hv.y + wv.z * hv.z + wv.w * hv.w;
            }
        }
#pragma unroll
        for (int n = 0; n < NB; ++n) hid[n][t] = fmaxf(acc[n], 0.f);
    }
    __syncthreads();
    {
        const float4* w2p = (const float4*)(W2 + (size_t)tt * DFF);
        float acc[NB / 2] = {};
        for (int u4 = 0; u4 < 64; ++u4) {
            float4 wv = w2p[u4];
#pragma unroll
            for (int m = 0; m < NB / 2; ++m) {
                int n = g * (NB / 2) + m;
                float4 hv = *(const float4*)&hid[n][u4 * 4];
                acc[m] += wv.x * hv.x + wv.y * hv.y + wv.z * hv.z + wv.w * hv.w;
            }
        }
        __syncthreads();
#pragma unroll
        for (int m = 0; m < NB / 2; ++m) {
            int n = g * (NB / 2) + m;
            hln[n][tt] = acc[m] + hs[n][tt];
        }
    }
    __syncthreads();
    for (int np = 0; np < NB / 2; ++np) {
        int n = np * 2 + g;
        float y = hln[n][tt];
        float mu = hred(y) * (1.f / 128.f);
        float d = y - mu;
        float var = hred(d * d) * (1.f / 128.f);
        out[(size_t)(nb + n) * D + tt] = d * rsqrtf(var + LN_EPS);
    }
}

extern "C" void kernel_launch(void* const* d_in, const int* in_sizes, int n_in,
                              void* d_out, int out_size, void* d_ws, size_t ws_size,
                              hipStream_t stream) {
    const float* bond = (const float*)d_in[0];
    const float* x    = (const float*)d_in[1];
    const float* basic= (const float*)d_in[2];
    const float* Wk   = (const float*)d_in[3];
    const float* Wq   = (const float*)d_in[4];
    const float* Wv   = (const float*)d_in[5];
    const float* Wdis = (const float*)d_in[6];
    const float* Wb   = (const float*)d_in[7];
    const float* W1   = (const float*)d_in[8];
    const float* W2   = (const float*)d_in[9];
    const float* g_ln = (const float*)d_in[10];
    const float* b_ln = (const float*)d_in[11];
    const int* src    = (const int*)d_in[12];
    const int* dst    = (const int*)d_in[13];
    float* out = (float*)d_out;

    // ws layout (105.6 MB, aliasing as in round 3):
    float* ws = (float*)d_ws;
    float* kbuf = ws;                                  // N*128  [abuf aliases]
    float* qbuf = kbuf + (size_t)N_NODES * D;          // N*128  [CSR aliases]
    float* pbuf = qbuf + (size_t)N_NODES * D;          // E*8
    unsigned* menc = (unsigned*)(pbuf + (size_t)N_EDGES * NH);  // N*8 [zeroed]
    float* ssum = (float*)(menc + (size_t)N_NODES * NH);        // N*8 [zeroed]
    float* ftb = ssum + (size_t)N_NODES * NH;          // N*128

    float* abuf = kbuf;     // reuse: kbuf dead after k_logits
    int* csr = (int*)qbuf;  // reuse: qbuf dead after k_logits
    int* deg      = csr;                 // N [zeroed after k_logits]
    int* scanout  = deg + N_NODES;       // N
    int* bsum     = scanout + N_NODES;   // 128
    int* rowstart = bsum + 128;          // N+1
    int* cursor   = rowstart + N_NODES + 1;  // N
    int* eidx     = cursor + N_NODES;    // E

    hipMemsetAsync(menc, 0, (size_t)N_NODES * NH * 2 * sizeof(float), stream);

    k_qkproj<<<N_NODES / 16, 128, 0, stream>>>(x, Wk, Wq, kbuf, qbuf);
    k_logits<<<(N_EDGES * NH) / 256, 256, 0, stream>>>(kbuf, qbuf, basic, Wdis,
                                                       src, dst, pbuf, menc);
    hipMemsetAsync(deg, 0, (size_t)N_NODES * sizeof(int), stream);
    k_exp<<<(N_EDGES * NH) / 256, 256, 0, stream>>>(dst, menc, pbuf, ssum);
    k_hist<<<N_EDGES / 256, 256, 0, stream>>>(dst, deg);
    k_scan1<<<NSCAN, SCAN_BS, 0, stream>>>(deg, scanout, bsum);
    k_scan2<<<1, 128, 0, stream>>>(bsum);
    k_scan3<<<(N_NODES + 255) / 256, 256, 0, stream>>>(scanout, bsum, rowstart, cursor);
    k_fill<<<N_EDGES / 256, 256, 0, stream>>>(dst, cursor, eidx);
    k_norm<<<(N_EDGES * NH) / 256, 256, 0, stream>>>(dst, ssum, pbuf, abuf);
    k_gather<<<N_NODES / GN, 256, 0, stream>>>(bond, Wv, abuf, rowstart, eidx, ftb);
    k_node<<<N_NODES / NB, 256, 0, stream>>>(ftb, x, Wb, W1, W2, g_ln, b_ln, out);
}

// Round 5
// 913.553 us; speedup vs baseline: 2.1495x; 1.0693x over previous
//
#include <hip/hip_runtime.h>
#include <hip/hip_bf16.h>

#define N_NODES 50000
#define N_EDGES 800000
#define D 128
#define NH 8
#define DH 16
#define DFF 256
#define LN_EPS 1e-5f
#define NB 8
#define GN 16
#define SCAN_BS 512
#define NSCAN ((N_NODES + SCAN_BS - 1) / SCAN_BS)  // 98

typedef __attribute__((ext_vector_type(8))) short bf16x8;
typedef __attribute__((ext_vector_type(4))) float f32x4;

// ---- monotonic float<->uint encoding for atomicMax on floats ----
__device__ __forceinline__ unsigned enc_f(float f) {
    unsigned u = __float_as_uint(f);
    return (u & 0x80000000u) ? ~u : (u | 0x80000000u);
}
__device__ __forceinline__ float dec_f(unsigned u) {
    return __uint_as_float((u & 0x80000000u) ? (u & 0x7fffffffu) : ~u);
}

__device__ __forceinline__ float wred(float v) {
#pragma unroll
    for (int o = 32; o; o >>= 1) v += __shfl_xor(v, o);
    return v;
}

// fp32 -> bf16 (RNE) bit helper
__device__ __forceinline__ short f2b(float f) {
    unsigned u = __float_as_uint(f);
    unsigned r = u + 0x7fffu + ((u >> 16) & 1u);
    return (short)(r >> 16);
}

// K1: q/k projections. 16 nodes per 128-thread block.
__global__ __launch_bounds__(128) void k_qkproj(
    const float* __restrict__ x, const float* __restrict__ Wk,
    const float* __restrict__ Wq, float* __restrict__ kout,
    float* __restrict__ qout) {
    __shared__ float xs[16][128];
    const int t = threadIdx.x;
    const int nb = blockIdx.x * 16;
#pragma unroll
    for (int r = 0; r < 16; ++r) xs[r][t] = x[(size_t)(nb + r) * D + t];
    __syncthreads();
    const float4* wk4 = (const float4*)(Wk + (size_t)t * D);
    const float4* wq4 = (const float4*)(Wq + (size_t)t * D);
    float ka[16] = {}, qa[16] = {};
#pragma unroll 4
    for (int i4 = 0; i4 < 32; ++i4) {
        float4 wk = wk4[i4], wq = wq4[i4];
#pragma unroll
        for (int r = 0; r < 16; ++r) {
            float4 xv = *(const float4*)&xs[r][i4 * 4];
            ka[r] += wk.x * xv.x + wk.y * xv.y + wk.z * xv.z + wk.w * xv.w;
            qa[r] += wq.x * xv.x + wq.y * xv.y + wq.z * xv.z + wq.w * xv.w;
        }
    }
#pragma unroll
    for (int r = 0; r < 16; ++r) {
        kout[(size_t)(nb + r) * D + t] = ka[r];
        qout[(size_t)(nb + r) * D + t] = qa[r];
    }
}

// K2: per-(edge,head) attention logit + segment max (encoded atomicMax).
__global__ __launch_bounds__(256) void k_logits(
    const float* __restrict__ kv, const float* __restrict__ qv,
    const float* __restrict__ basic, const float* __restrict__ Wdis,
    const int* __restrict__ src, const int* __restrict__ dst,
    float* __restrict__ logits, unsigned* __restrict__ menc) {
    int tid = blockIdx.x * 256 + threadIdx.x;
    int e = tid >> 3, h = tid & 7;
    int si = src[e], di = dst[e];
    const float4* kp = (const float4*)(kv + (size_t)si * D + h * DH);
    const float4* qp = (const float4*)(qv + (size_t)di * D + h * DH);
    float acc = 0.f;
#pragma unroll
    for (int i = 0; i < 4; ++i) {
        float4 a = kp[i], b = qp[i];
        acc += a.x * b.x + a.y * b.y + a.z * b.z + a.w * b.w;
    }
    float lg = acc * 0.25f + basic[e] * Wdis[h];
    logits[tid] = lg;
    atomicMax(&menc[(size_t)di * NH + h], enc_f(lg));
}

// K3: p = exp(logit - m[dst]); accumulate s. Overwrites logits with p.
__global__ __launch_bounds__(256) void k_exp(
    const int* __restrict__ dst, const unsigned* __restrict__ menc,
    float* __restrict__ logits, float* __restrict__ ssum) {
    int tid = blockIdx.x * 256 + threadIdx.x;
    int e = tid >> 3, h = tid & 7;
    int di = dst[e];
    float m = dec_f(menc[(size_t)di * NH + h]);
    float p = expf(logits[tid] - m);
    logits[tid] = p;
    atomicAdd(&ssum[(size_t)di * NH + h], p);
}

// CSR build ---------------------------------------------------------------
__global__ __launch_bounds__(256) void k_hist(const int* __restrict__ dst,
                                              int* __restrict__ deg) {
    int e = blockIdx.x * 256 + threadIdx.x;
    atomicAdd(&deg[dst[e]], 1);
}

__global__ __launch_bounds__(SCAN_BS) void k_scan1(
    const int* __restrict__ deg, int* __restrict__ scanout,
    int* __restrict__ bsum) {
    __shared__ int ss[SCAN_BS];
    const int t = threadIdx.x;
    const int i = blockIdx.x * SCAN_BS + t;
    int v = (i < N_NODES) ? deg[i] : 0;
    ss[t] = v;
    __syncthreads();
    for (int off = 1; off < SCAN_BS; off <<= 1) {
        int a = (t >= off) ? ss[t - off] : 0;
        __syncthreads();
        ss[t] += a;
        __syncthreads();
    }
    if (i < N_NODES) scanout[i] = ss[t] - v;  // exclusive within block
    if (t == SCAN_BS - 1) bsum[blockIdx.x] = ss[t];
}

__global__ __launch_bounds__(128) void k_scan2(int* __restrict__ bsum) {
    __shared__ int ss[128];
    const int t = threadIdx.x;
    int v = (t < NSCAN) ? bsum[t] : 0;
    ss[t] = v;
    __syncthreads();
    for (int off = 1; off < 128; off <<= 1) {
        int a = (t >= off) ? ss[t - off] : 0;
        __syncthreads();
        ss[t] += a;
        __syncthreads();
    }
    if (t < NSCAN) bsum[t] = ss[t] - v;  // exclusive across blocks
}

__global__ __launch_bounds__(256) void k_scan3(
    const int* __restrict__ scanout, const int* __restrict__ bsum,
    int* __restrict__ rowstart, int* __restrict__ cursor) {
    int i = blockIdx.x * 256 + threadIdx.x;
    if (i < N_NODES) {
        int rs = scanout[i] + bsum[i / SCAN_BS];
        rowstart[i] = rs;
        cursor[i] = rs;
    }
    if (i == 0) rowstart[N_NODES] = N_EDGES;
}

__global__ __launch_bounds__(256) void k_fill(const int* __restrict__ dst,
                                              int* __restrict__ cursor,
                                              int* __restrict__ eidx) {
    int e = blockIdx.x * 256 + threadIdx.x;
    int pos = atomicAdd(&cursor[dst[e]], 1);
    eidx[pos] = e;
}

// a = p / s[dst]
__global__ __launch_bounds__(256) void k_norm(
    const int* __restrict__ dst, const float* __restrict__ ssum,
    const float* __restrict__ pbuf, float* __restrict__ abuf) {
    int i = blockIdx.x * 256 + threadIdx.x;
    int e = i >> 3, h = i & 7;
    abuf[i] = pbuf[i] / ssum[(size_t)dst[e] * NH + h];
}

// K4: MFMA gather-GEMM. Per block: 16 dst nodes; Wv B-fragments in
// registers (wave owns 2 col-tiles == 2 heads); bond tiles staged bf16 in
// LDS (swizzled); run-length-merged LDS accumulate; coalesced ft store.
__global__ __launch_bounds__(256, 4) void k_gather(
    const float* __restrict__ bond, const float* __restrict__ Wv,
    const float* __restrict__ abuf, const int* __restrict__ rowstart,
    const int* __restrict__ eidx, float* __restrict__ ft) {
    __shared__ short Alds[64 * 128];   // bond tile bf16, swizzled chunks
    __shared__ float facc[GN * 128];
    __shared__ float salds[64 * 8];    // attn weights [edge][head]
    __shared__ int lnlds[64];          // local node id per edge row
    __shared__ int srs[GN + 1];
    const int t = threadIdx.x;
    const int n0 = blockIdx.x * GN;
    const int lane = t & 63, w = t >> 6;
    const int lr = lane & 15, lg = lane >> 4;

    if (t < GN + 1) srs[t] = rowstart[n0 + t];
    for (int i = t; i < GN * 128; i += 256) facc[i] = 0.f;

    // B fragments in registers: wave w owns col-tiles (heads) 2w, 2w+1.
    bf16x8 bfr[2][4];
#pragma unroll
    for (int nn = 0; nn < 2; ++nn) {
        int col = (2 * w + nn) * 16 + lr;
#pragma unroll
        for (int ks = 0; ks < 4; ++ks) {
            const float4* gp = (const float4*)(Wv + (size_t)col * D + ks * 32 + lg * 8);
            float4 f0 = gp[0], f1 = gp[1];
            bf16x8 v;
            v[0] = f2b(f0.x); v[1] = f2b(f0.y); v[2] = f2b(f0.z); v[3] = f2b(f0.w);
            v[4] = f2b(f1.x); v[5] = f2b(f1.y); v[6] = f2b(f1.z); v[7] = f2b(f1.w);
            bfr[nn][ks] = v;
        }
    }
    __syncthreads();
    const int rs0 = srs[0];
    const int total = srs[GN] - rs0;

    for (int base = 0; base < total; base += 64) {
        __syncthreads();  // prev tile fully consumed
        // stage bond tile (bf16, swizzled); eidx read direct (L1-hot)
#pragma unroll
        for (int i = 0; i < 4; ++i) {
            int cid = i * 256 + t;
            int row = cid >> 4, cx = cid & 15;
            int rel = base + row;
            bf16x8 v = {0, 0, 0, 0, 0, 0, 0, 0};
            if (rel < total) {
                int e = eidx[rs0 + rel];
                const float4* gp = (const float4*)(bond + (size_t)e * D + cx * 8);
                float4 f0 = gp[0], f1 = gp[1];
                v[0] = f2b(f0.x); v[1] = f2b(f0.y); v[2] = f2b(f0.z); v[3] = f2b(f0.w);
                v[4] = f2b(f1.x); v[5] = f2b(f1.y); v[6] = f2b(f1.z); v[7] = f2b(f1.w);
            }
            *(bf16x8*)&Alds[row * 128 + ((cx ^ (row & 7)) << 3)] = v;
        }
#pragma unroll
        for (int i = 0; i < 2; ++i) {
            int idx = i * 256 + t;
            int row = idx >> 3, rel = base + row;
            float a = 0.f;
            if (rel < total) a = abuf[(size_t)eidx[rs0 + rel] * NH + (idx & 7)];
            salds[idx] = a;
        }
        if (t < 64) {
            int rel = base + t, lnr = -1;
            if (rel < total) {
                int gpos = rs0 + rel;
                lnr = 0;
#pragma unroll
                for (int q = 1; q < GN; ++q) lnr += (gpos >= srs[q]);
            }
            lnlds[t] = lnr;
        }
        __syncthreads();
        // MFMA: all 64 edge rows x this wave's 2 col-tiles, K=128
        f32x4 acc[4][2];
#pragma unroll
        for (int m = 0; m < 4; ++m)
#pragma unroll
            for (int nn = 0; nn < 2; ++nn) acc[m][nn] = (f32x4){0.f, 0.f, 0.f, 0.f};
#pragma unroll
        for (int ks = 0; ks < 4; ++ks) {
            int chunk = ks * 4 + lg;
#pragma unroll
            for (int m = 0; m < 4; ++m) {
                int row = m * 16 + lr;
                bf16x8 af = *(const bf16x8*)&Alds[row * 128 + ((chunk ^ (row & 7)) << 3)];
#pragma unroll
                for (int nn = 0; nn < 2; ++nn)
                    acc[m][nn] = __builtin_amdgcn_mfma_f32_16x16x32_bf16(
                        af, bfr[nn][ks], acc[m][nn], 0, 0, 0);
            }
        }
        // epilogue: scale by a, run-length merge within each m-tile
#pragma unroll
        for (int nn = 0; nn < 2; ++nn) {
            int h = 2 * w + nn;
            int col = h * 16 + lr;
#pragma unroll
            for (int m = 0; m < 4; ++m) {
                float s = 0.f;
                int cur = -1;
#pragma unroll
                for (int r = 0; r < 4; ++r) {
                    int el = m * 16 + lg * 4 + r;
                    int ln = lnlds[el];
                    if (ln >= 0) {
                        float v = acc[m][nn][r] * salds[el * 8 + h];
                        if (ln != cur) {
                            if (cur >= 0) atomicAdd(&facc[cur * 128 + col], s);
                            s = 0.f;
                            cur = ln;
                        }
                        s += v;
                    }
                }
                if (cur >= 0) atomicAdd(&facc[cur * 128 + col], s);
            }
        }
    }
    __syncthreads();
    for (int i = t; i < GN * 128; i += 256)
        ft[(size_t)n0 * D + i] = facc[i];
}

// K5: per-node beta gate -> LN1 -> FFN -> residual -> LN2 -> f32 out.
__global__ __launch_bounds__(256) void k_node(
    const float* __restrict__ ft, const float* __restrict__ x,
    const float* __restrict__ Wb, const float* __restrict__ W1,
    const float* __restrict__ W2, const float* __restrict__ g_ln,
    const float* __restrict__ b_ln, float* __restrict__ out) {
    __shared__ float hln[NB][128];
    __shared__ float hs[NB][128];
    __shared__ float hid[NB][256];
    __shared__ float red[4];
    const int t = threadIdx.x;
    const int g = t >> 7;
    const int tt = t & 127;
    const int w = t >> 6;
    const int nb = blockIdx.x * NB;

    auto hred = [&](float v) -> float {
        float r = wred(v);
        if ((t & 63) == 0) red[w] = r;
        __syncthreads();
        float s = red[g * 2] + red[g * 2 + 1];
        __syncthreads();
        return s;
    };

    for (int np = 0; np < NB / 2; ++np) {
        int n = np * 2 + g;
        float fv = ft[(size_t)(nb + n) * D + tt];
        float xv = x[(size_t)(nb + n) * D + tt];
        float bsum = hred(fv * Wb[tt] + xv * Wb[128 + tt] + (fv - xv) * Wb[256 + tt]);
        float beta = 1.f / (1.f + expf(-bsum));
        float he = beta * xv + (1.f - beta) * fv;
        hs[n][tt] = he;
        float mu = hred(he) * (1.f / 128.f);
        float d = he - mu;
        float var = hred(d * d) * (1.f / 128.f);
        hln[n][tt] = d * rsqrtf(var + LN_EPS) * g_ln[tt] + b_ln[tt];
    }
    __syncthreads();
    {
        const float4* w1p = (const float4*)(W1 + (size_t)t * D);
        float acc[NB] = {};
        for (int i4 = 0; i4 < 32; ++i4) {
            float4 wv = w1p[i4];
#pragma unroll
            for (int n = 0; n < NB; ++n) {
                float4 hv = *(const float4*)&hln[n][i4 * 4];
                acc[n] += wv.x * hv.x + wv.y * hv.y + wv.z * hv.z + wv.w * hv.w;
            }
        }
#pragma unroll
        for (int n = 0; n < NB; ++n) hid[n][t] = fmaxf(acc[n], 0.f);
    }
    __syncthreads();
    {
        const float4* w2p = (const float4*)(W2 + (size_t)tt * DFF);
        float acc[NB / 2] = {};
        for (int u4 = 0; u4 < 64; ++u4) {
            float4 wv = w2p[u4];
#pragma unroll
            for (int m = 0; m < NB / 2; ++m) {
                int n = g * (NB / 2) + m;
                float4 hv = *(const float4*)&hid[n][u4 * 4];
                acc[m] += wv.x * hv.x + wv.y * hv.y + wv.z * hv.z + wv.w * hv.w;
            }
        }
        __syncthreads();
#pragma unroll
        for (int m = 0; m < NB / 2; ++m) {
            int n = g * (NB / 2) + m;
            hln[n][tt] = acc[m] + hs[n][tt];
        }
    }
    __syncthreads();
    for (int np = 0; np < NB / 2; ++np) {
        int n = np * 2 + g;
        float y = hln[n][tt];
        float mu = hred(y) * (1.f / 128.f);
        float d = y - mu;
        float var = hred(d * d) * (1.f / 128.f);
        out[(size_t)(nb + n) * D + tt] = d * rsqrtf(var + LN_EPS);
    }
}

extern "C" void kernel_launch(void* const* d_in, const int* in_sizes, int n_in,
                              void* d_out, int out_size, void* d_ws, size_t ws_size,
                              hipStream_t stream) {
    const float* bond = (const float*)d_in[0];
    const float* x    = (const float*)d_in[1];
    const float* basic= (const float*)d_in[2];
    const float* Wk   = (const float*)d_in[3];
    const float* Wq   = (const float*)d_in[4];
    const float* Wv   = (const float*)d_in[5];
    const float* Wdis = (const float*)d_in[6];
    const float* Wb   = (const float*)d_in[7];
    const float* W1   = (const float*)d_in[8];
    const float* W2   = (const float*)d_in[9];
    const float* g_ln = (const float*)d_in[10];
    const float* b_ln = (const float*)d_in[11];
    const int* src    = (const int*)d_in[12];
    const int* dst    = (const int*)d_in[13];
    float* out = (float*)d_out;

    // ws layout (105.6 MB, aliasing as before):
    float* ws = (float*)d_ws;
    float* kbuf = ws;                                  // N*128  [abuf aliases]
    float* qbuf = kbuf + (size_t)N_NODES * D;          // N*128  [CSR aliases]
    float* pbuf = qbuf + (size_t)N_NODES * D;          // E*8
    unsigned* menc = (unsigned*)(pbuf + (size_t)N_EDGES * NH);  // N*8 [zeroed]
    float* ssum = (float*)(menc + (size_t)N_NODES * NH);        // N*8 [zeroed]
    float* ftb = ssum + (size_t)N_NODES * NH;          // N*128

    float* abuf = kbuf;     // reuse: kbuf dead after k_logits
    int* csr = (int*)qbuf;  // reuse: qbuf dead after k_logits
    int* deg      = csr;                 // N [zeroed after k_logits]
    int* scanout  = deg + N_NODES;       // N
    int* bsum     = scanout + N_NODES;   // 128
    int* rowstart = bsum + 128;          // N+1
    int* cursor   = rowstart + N_NODES + 1;  // N
    int* eidx     = cursor + N_NODES;    // E

    hipMemsetAsync(menc, 0, (size_t)N_NODES * NH * 2 * sizeof(float), stream);

    k_qkproj<<<N_NODES / 16, 128, 0, stream>>>(x, Wk, Wq, kbuf, qbuf);
    k_logits<<<(N_EDGES * NH) / 256, 256, 0, stream>>>(kbuf, qbuf, basic, Wdis,
                                                       src, dst, pbuf, menc);
    hipMemsetAsync(deg, 0, (size_t)N_NODES * sizeof(int), stream);
    k_exp<<<(N_EDGES * NH) / 256, 256, 0, stream>>>(dst, menc, pbuf, ssum);
    k_hist<<<N_EDGES / 256, 256, 0, stream>>>(dst, deg);
    k_scan1<<<NSCAN, SCAN_BS, 0, stream>>>(deg, scanout, bsum);
    k_scan2<<<1, 128, 0, stream>>>(bsum);
    k_scan3<<<(N_NODES + 255) / 256, 256, 0, stream>>>(scanout, bsum, rowstart, cursor);
    k_fill<<<N_EDGES / 256, 256, 0, stream>>>(dst, cursor, eidx);
    k_norm<<<(N_EDGES * NH) / 256, 256, 0, stream>>>(dst, ssum, pbuf, abuf);
    k_gather<<<N_NODES / GN, 256, 0, stream>>>(bond, Wv, abuf, rowstart, eidx, ftb);
    k_node<<<N_NODES / NB, 256, 0, stream>>>(ftb, x, Wb, W1, W2, g_ln, b_ln, out);
}

// Round 6
// 707.566 us; speedup vs baseline: 2.7753x; 1.2911x over previous
//
#include <hip/hip_runtime.h>
#include <hip/hip_bf16.h>

#define N_NODES 50000
#define N_EDGES 800000
#define D 128
#define NH 8
#define DH 16
#define DFF 256
#define LN_EPS 1e-5f
#define GN 16
#define NPB 32
#define SCAN_BS 512
#define NSCAN ((N_NODES + SCAN_BS - 1) / SCAN_BS)  // 98

typedef __attribute__((ext_vector_type(8))) short bf16x8;
typedef __attribute__((ext_vector_type(4))) float f32x4;

// ---- monotonic float<->uint encoding for atomicMax on floats ----
__device__ __forceinline__ unsigned enc_f(float f) {
    unsigned u = __float_as_uint(f);
    return (u & 0x80000000u) ? ~u : (u | 0x80000000u);
}
__device__ __forceinline__ float dec_f(unsigned u) {
    return __uint_as_float((u & 0x80000000u) ? (u & 0x7fffffffu) : ~u);
}

__device__ __forceinline__ float wred(float v) {
#pragma unroll
    for (int o = 32; o; o >>= 1) v += __shfl_xor(v, o);
    return v;
}

// fp32 -> bf16 (RNE) bit helper
__device__ __forceinline__ short f2b(float f) {
    unsigned u = __float_as_uint(f);
    unsigned r = u + 0x7fffu + ((u >> 16) & 1u);
    return (short)(r >> 16);
}

// K1: q/k projections. 16 nodes per 128-thread block.
__global__ __launch_bounds__(128) void k_qkproj(
    const float* __restrict__ x, const float* __restrict__ Wk,
    const float* __restrict__ Wq, float* __restrict__ kout,
    float* __restrict__ qout) {
    __shared__ float xs[16][128];
    const int t = threadIdx.x;
    const int nb = blockIdx.x * 16;
#pragma unroll
    for (int r = 0; r < 16; ++r) xs[r][t] = x[(size_t)(nb + r) * D + t];
    __syncthreads();
    const float4* wk4 = (const float4*)(Wk + (size_t)t * D);
    const float4* wq4 = (const float4*)(Wq + (size_t)t * D);
    float ka[16] = {}, qa[16] = {};
#pragma unroll 4
    for (int i4 = 0; i4 < 32; ++i4) {
        float4 wk = wk4[i4], wq = wq4[i4];
#pragma unroll
        for (int r = 0; r < 16; ++r) {
            float4 xv = *(const float4*)&xs[r][i4 * 4];
            ka[r] += wk.x * xv.x + wk.y * xv.y + wk.z * xv.z + wk.w * xv.w;
            qa[r] += wq.x * xv.x + wq.y * xv.y + wq.z * xv.z + wq.w * xv.w;
        }
    }
#pragma unroll
    for (int r = 0; r < 16; ++r) {
        kout[(size_t)(nb + r) * D + t] = ka[r];
        qout[(size_t)(nb + r) * D + t] = qa[r];
    }
}

// K2: per-(edge,head) attention logit + segment max (encoded atomicMax).
__global__ __launch_bounds__(256) void k_logits(
    const float* __restrict__ kv, const float* __restrict__ qv,
    const float* __restrict__ basic, const float* __restrict__ Wdis,
    const int* __restrict__ src, const int* __restrict__ dst,
    float* __restrict__ logits, unsigned* __restrict__ menc) {
    int tid = blockIdx.x * 256 + threadIdx.x;
    int e = tid >> 3, h = tid & 7;
    int si = src[e], di = dst[e];
    const float4* kp = (const float4*)(kv + (size_t)si * D + h * DH);
    const float4* qp = (const float4*)(qv + (size_t)di * D + h * DH);
    float acc = 0.f;
#pragma unroll
    for (int i = 0; i < 4; ++i) {
        float4 a = kp[i], b = qp[i];
        acc += a.x * b.x + a.y * b.y + a.z * b.z + a.w * b.w;
    }
    float lg = acc * 0.25f + basic[e] * Wdis[h];
    logits[tid] = lg;
    atomicMax(&menc[(size_t)di * NH + h], enc_f(lg));
}

// K3: p = exp(logit - m[dst]); accumulate s. Overwrites logits with p.
__global__ __launch_bounds__(256) void k_exp(
    const int* __restrict__ dst, const unsigned* __restrict__ menc,
    float* __restrict__ logits, float* __restrict__ ssum) {
    int tid = blockIdx.x * 256 + threadIdx.x;
    int e = tid >> 3, h = tid & 7;
    int di = dst[e];
    float m = dec_f(menc[(size_t)di * NH + h]);
    float p = expf(logits[tid] - m);
    logits[tid] = p;
    atomicAdd(&ssum[(size_t)di * NH + h], p);
}

// CSR build ---------------------------------------------------------------
__global__ __launch_bounds__(256) void k_hist(const int* __restrict__ dst,
                                              int* __restrict__ deg) {
    int e = blockIdx.x * 256 + threadIdx.x;
    atomicAdd(&deg[dst[e]], 1);
}

__global__ __launch_bounds__(SCAN_BS) void k_scan1(
    const int* __restrict__ deg, int* __restrict__ scanout,
    int* __restrict__ bsum) {
    __shared__ int ss[SCAN_BS];
    const int t = threadIdx.x;
    const int i = blockIdx.x * SCAN_BS + t;
    int v = (i < N_NODES) ? deg[i] : 0;
    ss[t] = v;
    __syncthreads();
    for (int off = 1; off < SCAN_BS; off <<= 1) {
        int a = (t >= off) ? ss[t - off] : 0;
        __syncthreads();
        ss[t] += a;
        __syncthreads();
    }
    if (i < N_NODES) scanout[i] = ss[t] - v;  // exclusive within block
    if (t == SCAN_BS - 1) bsum[blockIdx.x] = ss[t];
}

__global__ __launch_bounds__(128) void k_scan2(int* __restrict__ bsum) {
    __shared__ int ss[128];
    const int t = threadIdx.x;
    int v = (t < NSCAN) ? bsum[t] : 0;
    ss[t] = v;
    __syncthreads();
    for (int off = 1; off < 128; off <<= 1) {
        int a = (t >= off) ? ss[t - off] : 0;
        __syncthreads();
        ss[t] += a;
        __syncthreads();
    }
    if (t < NSCAN) bsum[t] = ss[t] - v;  // exclusive across blocks
}

__global__ __launch_bounds__(256) void k_scan3(
    const int* __restrict__ scanout, const int* __restrict__ bsum,
    int* __restrict__ rowstart, int* __restrict__ cursor) {
    int i = blockIdx.x * 256 + threadIdx.x;
    if (i < N_NODES) {
        int rs = scanout[i] + bsum[i / SCAN_BS];
        rowstart[i] = rs;
        cursor[i] = rs;
    }
    if (i == 0) rowstart[N_NODES] = N_EDGES;
}

__global__ __launch_bounds__(256) void k_fill(const int* __restrict__ dst,
                                              int* __restrict__ cursor,
                                              int* __restrict__ eidx) {
    int e = blockIdx.x * 256 + threadIdx.x;
    int pos = atomicAdd(&cursor[dst[e]], 1);
    eidx[pos] = e;
}

// a = p / s[dst]
__global__ __launch_bounds__(256) void k_norm(
    const int* __restrict__ dst, const float* __restrict__ ssum,
    const float* __restrict__ pbuf, float* __restrict__ abuf) {
    int i = blockIdx.x * 256 + threadIdx.x;
    int e = i >> 3, h = i & 7;
    abuf[i] = pbuf[i] / ssum[(size_t)dst[e] * NH + h];
}

// K4: MFMA gather-GEMM. Per block: 16 dst nodes; Wv B-fragments in
// registers (wave owns 2 col-tiles == 2 heads); bond tiles staged bf16 in
// LDS (swizzled); run-length-merged LDS accumulate; coalesced ft store.
__global__ __launch_bounds__(256, 4) void k_gather(
    const float* __restrict__ bond, const float* __restrict__ Wv,
    const float* __restrict__ abuf, const int* __restrict__ rowstart,
    const int* __restrict__ eidx, float* __restrict__ ft) {
    __shared__ short Alds[64 * 128];   // bond tile bf16, swizzled chunks
    __shared__ float facc[GN * 128];
    __shared__ float salds[64 * 8];    // attn weights [edge][head]
    __shared__ int lnlds[64];          // local node id per edge row
    __shared__ int srs[GN + 1];
    const int t = threadIdx.x;
    const int n0 = blockIdx.x * GN;
    const int lane = t & 63, w = t >> 6;
    const int lr = lane & 15, lg = lane >> 4;

    if (t < GN + 1) srs[t] = rowstart[n0 + t];
    for (int i = t; i < GN * 128; i += 256) facc[i] = 0.f;

    // B fragments in registers: wave w owns col-tiles (heads) 2w, 2w+1.
    bf16x8 bfr[2][4];
#pragma unroll
    for (int nn = 0; nn < 2; ++nn) {
        int col = (2 * w + nn) * 16 + lr;
#pragma unroll
        for (int ks = 0; ks < 4; ++ks) {
            const float4* gp = (const float4*)(Wv + (size_t)col * D + ks * 32 + lg * 8);
            float4 f0 = gp[0], f1 = gp[1];
            bf16x8 v;
            v[0] = f2b(f0.x); v[1] = f2b(f0.y); v[2] = f2b(f0.z); v[3] = f2b(f0.w);
            v[4] = f2b(f1.x); v[5] = f2b(f1.y); v[6] = f2b(f1.z); v[7] = f2b(f1.w);
            bfr[nn][ks] = v;
        }
    }
    __syncthreads();
    const int rs0 = srs[0];
    const int total = srs[GN] - rs0;

    for (int base = 0; base < total; base += 64) {
        __syncthreads();  // prev tile fully consumed
        // stage bond tile (bf16, swizzled); eidx read direct (L1-hot)
#pragma unroll
        for (int i = 0; i < 4; ++i) {
            int cid = i * 256 + t;
            int row = cid >> 4, cx = cid & 15;
            int rel = base + row;
            bf16x8 v = {0, 0, 0, 0, 0, 0, 0, 0};
            if (rel < total) {
                int e = eidx[rs0 + rel];
                const float4* gp = (const float4*)(bond + (size_t)e * D + cx * 8);
                float4 f0 = gp[0], f1 = gp[1];
                v[0] = f2b(f0.x); v[1] = f2b(f0.y); v[2] = f2b(f0.z); v[3] = f2b(f0.w);
                v[4] = f2b(f1.x); v[5] = f2b(f1.y); v[6] = f2b(f1.z); v[7] = f2b(f1.w);
            }
            *(bf16x8*)&Alds[row * 128 + ((cx ^ (row & 7)) << 3)] = v;
        }
#pragma unroll
        for (int i = 0; i < 2; ++i) {
            int idx = i * 256 + t;
            int row = idx >> 3, rel = base + row;
            float a = 0.f;
            if (rel < total) a = abuf[(size_t)eidx[rs0 + rel] * NH + (idx & 7)];
            salds[idx] = a;
        }
        if (t < 64) {
            int rel = base + t, lnr = -1;
            if (rel < total) {
                int gpos = rs0 + rel;
                lnr = 0;
#pragma unroll
                for (int q = 1; q < GN; ++q) lnr += (gpos >= srs[q]);
            }
            lnlds[t] = lnr;
        }
        __syncthreads();
        // MFMA: all 64 edge rows x this wave's 2 col-tiles, K=128
        f32x4 acc[4][2];
#pragma unroll
        for (int m = 0; m < 4; ++m)
#pragma unroll
            for (int nn = 0; nn < 2; ++nn) acc[m][nn] = (f32x4){0.f, 0.f, 0.f, 0.f};
#pragma unroll
        for (int ks = 0; ks < 4; ++ks) {
            int chunk = ks * 4 + lg;
#pragma unroll
            for (int m = 0; m < 4; ++m) {
                int row = m * 16 + lr;
                bf16x8 af = *(const bf16x8*)&Alds[row * 128 + ((chunk ^ (row & 7)) << 3)];
#pragma unroll
                for (int nn = 0; nn < 2; ++nn)
                    acc[m][nn] = __builtin_amdgcn_mfma_f32_16x16x32_bf16(
                        af, bfr[nn][ks], acc[m][nn], 0, 0, 0);
            }
        }
        // epilogue: scale by a, run-length merge within each m-tile
#pragma unroll
        for (int nn = 0; nn < 2; ++nn) {
            int h = 2 * w + nn;
            int col = h * 16 + lr;
#pragma unroll
            for (int m = 0; m < 4; ++m) {
                float s = 0.f;
                int cur = -1;
#pragma unroll
                for (int r = 0; r < 4; ++r) {
                    int el = m * 16 + lg * 4 + r;
                    int ln = lnlds[el];
                    if (ln >= 0) {
                        float v = acc[m][nn][r] * salds[el * 8 + h];
                        if (ln != cur) {
                            if (cur >= 0) atomicAdd(&facc[cur * 128 + col], s);
                            s = 0.f;
                            cur = ln;
                        }
                        s += v;
                    }
                }
                if (cur >= 0) atomicAdd(&facc[cur * 128 + col], s);
            }
        }
    }
    __syncthreads();
    for (int i = t; i < GN * 128; i += 256)
        ft[(size_t)n0 * D + i] = facc[i];
}

// K5: MFMA node kernel. 32 nodes/block, 4 waves.
// P1: beta+LN1 (per-wave) -> bf16 A-tile.  P2: MFMA hidden=relu(h@W1.T).
// P3: MFMA y=hid@W2.T + residual.  P4: LN2 -> f32 out.
__global__ __launch_bounds__(256, 2) void k_node(
    const float* __restrict__ ft, const float* __restrict__ x,
    const float* __restrict__ Wb, const float* __restrict__ W1,
    const float* __restrict__ W2, const float* __restrict__ g_ln,
    const float* __restrict__ b_ln, float* __restrict__ out) {
    __shared__ float hs[NPB][132];     // he residual fp32 (padded)
    __shared__ short hA[NPB * 128];    // LN1 out bf16, chunk-swizzled
    __shared__ short hid[NPB * 256];   // hidden bf16, chunk-swizzled
    __shared__ float ylds[NPB][132];   // y fp32 (padded)
    const int t = threadIdx.x;
    const int lane = t & 63, w = t >> 6;
    const int lr = lane & 15, lg = lane >> 4;
    const int n0 = blockIdx.x * NPB;
    const int c0 = lane * 2;

    // ---- Phase 1: beta gate + LN1 (wave w owns nodes w*8..w*8+7) ----
    const float2 wb0 = *(const float2*)&Wb[c0];
    const float2 wb1 = *(const float2*)&Wb[128 + c0];
    const float2 wb2 = *(const float2*)&Wb[256 + c0];
    const float2 gv = *(const float2*)&g_ln[c0];
    const float2 bv = *(const float2*)&b_ln[c0];
#pragma unroll
    for (int i = 0; i < 8; ++i) {
        int n = w * 8 + i;
        int gn = n0 + n;
        float2 fv = {0.f, 0.f}, xv = {0.f, 0.f};
        if (gn < N_NODES) {
            fv = *(const float2*)&ft[(size_t)gn * D + c0];
            xv = *(const float2*)&x[(size_t)gn * D + c0];
        }
        float part = fv.x * wb0.x + fv.y * wb0.y + xv.x * wb1.x + xv.y * wb1.y +
                     (fv.x - xv.x) * wb2.x + (fv.y - xv.y) * wb2.y;
        float beta = 1.f / (1.f + expf(-wred(part)));
        float hex = beta * xv.x + (1.f - beta) * fv.x;
        float hey = beta * xv.y + (1.f - beta) * fv.y;
        hs[n][c0] = hex;
        hs[n][c0 + 1] = hey;
        float mu = wred(hex + hey) * (1.f / 128.f);
        float dx = hex - mu, dy = hey - mu;
        float var = wred(dx * dx + dy * dy) * (1.f / 128.f);
        float rs = rsqrtf(var + LN_EPS);
        float h0 = dx * rs * gv.x + bv.x;
        float h1 = dy * rs * gv.y + bv.y;
        unsigned u = (unsigned)(unsigned short)f2b(h0) |
                     ((unsigned)(unsigned short)f2b(h1) << 16);
        int phys = (lane >> 2) ^ (n & 7);
        ((unsigned*)hA)[n * 64 + phys * 4 + (lane & 3)] = u;
    }
    __syncthreads();

    // ---- Phase 2: hidden = relu(h @ W1.T); wave owns ffn cols w*64..+63 ----
    {
        bf16x8 b1[4][4];
#pragma unroll
        for (int nt = 0; nt < 4; ++nt) {
            int col = w * 64 + nt * 16 + lr;
#pragma unroll
            for (int ks = 0; ks < 4; ++ks) {
                const float4* gp = (const float4*)(W1 + (size_t)col * D + ks * 32 + lg * 8);
                float4 f0 = gp[0], f1 = gp[1];
                bf16x8 v;
                v[0] = f2b(f0.x); v[1] = f2b(f0.y); v[2] = f2b(f0.z); v[3] = f2b(f0.w);
                v[4] = f2b(f1.x); v[5] = f2b(f1.y); v[6] = f2b(f1.z); v[7] = f2b(f1.w);
                b1[nt][ks] = v;
            }
        }
        f32x4 acc1[2][4];
#pragma unroll
        for (int m = 0; m < 2; ++m)
#pragma unroll
            for (int nt = 0; nt < 4; ++nt) acc1[m][nt] = (f32x4){0.f, 0.f, 0.f, 0.f};
#pragma unroll
        for (int ks = 0; ks < 4; ++ks) {
            int chunk = ks * 4 + lg;
#pragma unroll
            for (int m = 0; m < 2; ++m) {
                int row = m * 16 + lr;
                bf16x8 af = *(const bf16x8*)&hA[row * 128 + ((chunk ^ (row & 7)) << 3)];
#pragma unroll
                for (int nt = 0; nt < 4; ++nt)
                    acc1[m][nt] = __builtin_amdgcn_mfma_f32_16x16x32_bf16(
                        af, b1[nt][ks], acc1[m][nt], 0, 0, 0);
            }
        }
#pragma unroll
        for (int m = 0; m < 2; ++m)
#pragma unroll
            for (int nt = 0; nt < 4; ++nt)
#pragma unroll
                for (int r = 0; r < 4; ++r) {
                    int node = m * 16 + lg * 4 + r;
                    int col = w * 64 + nt * 16 + lr;
                    float v = fmaxf(acc1[m][nt][r], 0.f);
                    hid[node * 256 + (((col >> 3) ^ (node & 7)) << 3) + (col & 7)] = f2b(v);
                }
    }
    __syncthreads();

    // ---- Phase 3: y = hid @ W2.T + residual; wave owns d cols w*32..+31 ----
    {
        bf16x8 b2[2][8];
#pragma unroll
        for (int nt = 0; nt < 2; ++nt) {
            int col = w * 32 + nt * 16 + lr;
#pragma unroll
            for (int ks = 0; ks < 8; ++ks) {
                const float4* gp = (const float4*)(W2 + (size_t)col * DFF + ks * 32 + lg * 8);
                float4 f0 = gp[0], f1 = gp[1];
                bf16x8 v;
                v[0] = f2b(f0.x); v[1] = f2b(f0.y); v[2] = f2b(f0.z); v[3] = f2b(f0.w);
                v[4] = f2b(f1.x); v[5] = f2b(f1.y); v[6] = f2b(f1.z); v[7] = f2b(f1.w);
                b2[nt][ks] = v;
            }
        }
        f32x4 acc2[2][2];
#pragma unroll
        for (int m = 0; m < 2; ++m)
#pragma unroll
            for (int nt = 0; nt < 2; ++nt) acc2[m][nt] = (f32x4){0.f, 0.f, 0.f, 0.f};
#pragma unroll
        for (int ks = 0; ks < 8; ++ks) {
            int chunk = ks * 4 + lg;
#pragma unroll
            for (int m = 0; m < 2; ++m) {
                int row = m * 16 + lr;
                bf16x8 af = *(const bf16x8*)&hid[row * 256 + ((chunk ^ (row & 7)) << 3)];
#pragma unroll
                for (int nt = 0; nt < 2; ++nt)
                    acc2[m][nt] = __builtin_amdgcn_mfma_f32_16x16x32_bf16(
                        af, b2[nt][ks], acc2[m][nt], 0, 0, 0);
            }
        }
#pragma unroll
        for (int m = 0; m < 2; ++m)
#pragma unroll
            for (int nt = 0; nt < 2; ++nt)
#pragma unroll
                for (int r = 0; r < 4; ++r) {
                    int node = m * 16 + lg * 4 + r;
                    int col = w * 32 + nt * 16 + lr;
                    ylds[node][col] = acc2[m][nt][r] + hs[node][col];
                }
    }
    __syncthreads();

    // ---- Phase 4: LN2 (non-affine) -> out; wave w owns nodes w*8..+7 ----
#pragma unroll
    for (int i = 0; i < 8; ++i) {
        int n = w * 8 + i;
        int gn = n0 + n;
        float y0 = ylds[n][c0], y1 = ylds[n][c0 + 1];
        float mu = wred(y0 + y1) * (1.f / 128.f);
        float d0 = y0 - mu, d1 = y1 - mu;
        float var = wred(d0 * d0 + d1 * d1) * (1.f / 128.f);
        float rs = rsqrtf(var + LN_EPS);
        if (gn < N_NODES) {
            float2 o = {d0 * rs, d1 * rs};
            *(float2*)&out[(size_t)gn * D + c0] = o;
        }
    }
}

extern "C" void kernel_launch(void* const* d_in, const int* in_sizes, int n_in,
                              void* d_out, int out_size, void* d_ws, size_t ws_size,
                              hipStream_t stream) {
    const float* bond = (const float*)d_in[0];
    const float* x    = (const float*)d_in[1];
    const float* basic= (const float*)d_in[2];
    const float* Wk   = (const float*)d_in[3];
    const float* Wq   = (const float*)d_in[4];
    const float* Wv   = (const float*)d_in[5];
    const float* Wdis = (const float*)d_in[6];
    const float* Wb   = (const float*)d_in[7];
    const float* W1   = (const float*)d_in[8];
    const float* W2   = (const float*)d_in[9];
    const float* g_ln = (const float*)d_in[10];
    const float* b_ln = (const float*)d_in[11];
    const int* src    = (const int*)d_in[12];
    const int* dst    = (const int*)d_in[13];
    float* out = (float*)d_out;

    // ws layout (105.6 MB, aliasing as before):
    float* ws = (float*)d_ws;
    float* kbuf = ws;                                  // N*128  [abuf aliases]
    float* qbuf = kbuf + (size_t)N_NODES * D;          // N*128  [CSR aliases]
    float* pbuf = qbuf + (size_t)N_NODES * D;          // E*8
    unsigned* menc = (unsigned*)(pbuf + (size_t)N_EDGES * NH);  // N*8 [zeroed]
    float* ssum = (float*)(menc + (size_t)N_NODES * NH);        // N*8 [zeroed]
    float* ftb = ssum + (size_t)N_NODES * NH;          // N*128

    float* abuf = kbuf;     // reuse: kbuf dead after k_logits
    int* csr = (int*)qbuf;  // reuse: qbuf dead after k_logits
    int* deg      = csr;                 // N [zeroed after k_logits]
    int* scanout  = deg + N_NODES;       // N
    int* bsum     = scanout + N_NODES;   // 128
    int* rowstart = bsum + 128;          // N+1
    int* cursor   = rowstart + N_NODES + 1;  // N
    int* eidx     = cursor + N_NODES;    // E

    hipMemsetAsync(menc, 0, (size_t)N_NODES * NH * 2 * sizeof(float), stream);

    k_qkproj<<<N_NODES / 16, 128, 0, stream>>>(x, Wk, Wq, kbuf, qbuf);
    k_logits<<<(N_EDGES * NH) / 256, 256, 0, stream>>>(kbuf, qbuf, basic, Wdis,
                                                       src, dst, pbuf, menc);
    hipMemsetAsync(deg, 0, (size_t)N_NODES * sizeof(int), stream);
    k_exp<<<(N_EDGES * NH) / 256, 256, 0, stream>>>(dst, menc, pbuf, ssum);
    k_hist<<<N_EDGES / 256, 256, 0, stream>>>(dst, deg);
    k_scan1<<<NSCAN, SCAN_BS, 0, stream>>>(deg, scanout, bsum);
    k_scan2<<<1, 128, 0, stream>>>(bsum);
    k_scan3<<<(N_NODES + 255) / 256, 256, 0, stream>>>(scanout, bsum, rowstart, cursor);
    k_fill<<<N_EDGES / 256, 256, 0, stream>>>(dst, cursor, eidx);
    k_norm<<<(N_EDGES * NH) / 256, 256, 0, stream>>>(dst, ssum, pbuf, abuf);
    k_gather<<<N_NODES / GN, 256, 0, stream>>>(bond, Wv, abuf, rowstart, eidx, ftb);
    k_node<<<(N_NODES + NPB - 1) / NPB, 256, 0, stream>>>(ftb, x, Wb, W1, W2,
                                                          g_ln, b_ln, out);
}